// Round 9
// baseline (255.833 us; speedup 1.0000x reference)
//
#include <hip/hip_runtime.h>
#include <math.h>

#define NNODES 100000
#define NEDGES 1600000
#define DD 64
#define EPS 1e-8f

#define NBUCK 1024
#define BW 98
#define BIN_BLOCKS 256
#define BIN_CHUNK ((NEDGES + BIN_BLOCKS - 1) / BIN_BLOCKS)  // 6250
#define BIN_CAP 12
#define SORT_CAP 4096
#define NTILES (NNODES / 16)   // 6250, exact
#define TILEA 1250             // GEMM tiles done in kernel1 (overlapping histo)
#define CAP4 512

typedef unsigned short us8 __attribute__((ext_vector_type(8)));
typedef short short8 __attribute__((ext_vector_type(8)));
typedef float f32x4 __attribute__((ext_vector_type(4)));

__device__ __forceinline__ float wave_sum(float v) {
    #pragma unroll
    for (int off = 32; off; off >>= 1) v += __shfl_xor(v, off, 64);
    return v;
}

__device__ __forceinline__ float hinner(float u, float v, float sgn) {
    return wave_sum(sgn * u * v);
}

__device__ __forceinline__ float cross_ratio(float r0, float r1, float r2, float r3, float sgn) {
    float A = hinner(r0, r2, sgn);
    float B = hinner(r1, r3, sgn);
    float C = hinner(r0, r3, sgn);
    float Dv = hinner(r1, r2, sgn);
    return (A * B) / (C * Dv + EPS);
}

__device__ __forceinline__ float restore_scale(float cr_i, float cr_c) {
    float ratio = cr_i / (cr_c + EPS);
    bool cond = (!__builtin_isnan(cr_c)) && (!__builtin_isnan(cr_i)) &&
                (fabsf(cr_c) > EPS) && (fabsf(cr_i) > EPS) && (ratio > EPS);
    float s = 1.0f;
    if (cond) {
        s = sqrtf(fabsf(ratio));
        if (!__builtin_isfinite(s)) s = 1.0f;
    }
    return s;
}

__device__ __forceinline__ unsigned short f2bf(float f) {
    unsigned u = __float_as_uint(f);
    unsigned r = (u + 0x7fffu + ((u >> 16) & 1u)) >> 16;
    return (unsigned short)r;
}

__device__ __forceinline__ float bf2f(unsigned short b) {
    return __uint_as_float(((unsigned)b) << 16);
}

__device__ __forceinline__ float bcast(float v, int lane) {
    return __int_as_float(__builtin_amdgcn_readlane(__float_as_int(v), lane));
}

// load one weight matrix as split-bf16 B fragments in VGPRs
__device__ __forceinline__ void load_bfrags(const float* __restrict__ W, int lane,
                                            short8 bhi[4][2], short8 blo[4][2]) {
    int c = lane & 15, q = lane >> 4;
    #pragma unroll
    for (int t = 0; t < 4; t++)
        #pragma unroll
        for (int h = 0; h < 2; h++) {
            short8 hi8, lo8;
            #pragma unroll
            for (int j = 0; j < 8; j++) {
                float w = W[(h * 32 + q * 8 + j) * DD + t * 16 + c];
                unsigned short hb = f2bf(w);
                float r = w - bf2f(hb);
                hi8[j] = (short)hb;
                lo8[j] = (short)f2bf(r);
            }
            bhi[t][h] = hi8;
            blo[t][h] = lo8;
        }
}

__device__ __forceinline__ void build_a8(const float av[8], short8& hi, short8& lo) {
    short8 h8, l8;
    #pragma unroll
    for (int j = 0; j < 8; j++) {
        unsigned short hb = f2bf(av[j]);
        float r = av[j] - bf2f(hb);
        h8[j] = (short)hb;
        l8[j] = (short)f2bf(r);
    }
    hi = h8;
    lo = l8;
}

__device__ __forceinline__ void build_a(const float* p, short8& hi, short8& lo) {
    float4 f0 = *(const float4*)p;
    float4 f1 = *(const float4*)(p + 4);
    float av[8] = {f0.x, f0.y, f0.z, f0.w, f1.x, f1.y, f1.z, f1.w};
    build_a8(av, hi, lo);
}

#define MFMA3R(cacc, ahi, alo, BH, BL, t, h)                                     \
    cacc = __builtin_amdgcn_mfma_f32_16x16x32_bf16(ahi, BH[t][h], cacc, 0, 0, 0); \
    cacc = __builtin_amdgcn_mfma_f32_16x16x32_bf16(alo, BH[t][h], cacc, 0, 0, 0); \
    cacc = __builtin_amdgcn_mfma_f32_16x16x32_bf16(ahi, BL[t][h], cacc, 0, 0, 0);

// shared GEMM-tile body for the l0 layer (x@W0 -> normalize -> h0b bf16)
__device__ __forceinline__ void l0_tiles(const float* __restrict__ x,
                                         const float* __restrict__ W0,
                                         const float* __restrict__ b0,
                                         unsigned short* __restrict__ h0b,
                                         int lane, int wid, int nw, int tlo, int thi) {
    int c = lane & 15, q = lane >> 4;
    short8 bhi[4][2], blo[4][2];
    load_bfrags(W0, lane, bhi, blo);
    float badd[4];
    #pragma unroll
    for (int t = 0; t < 4; t++) badd[t] = b0[t * 16 + c];
    for (int tile = tlo + wid; tile < thi; tile += nw) {
        int R = tile * 16;
        f32x4 cc[4] = {{0, 0, 0, 0}, {0, 0, 0, 0}, {0, 0, 0, 0}, {0, 0, 0, 0}};
        #pragma unroll
        for (int hh = 0; hh < 2; hh++) {
            short8 ahi, alo;
            build_a(x + ((size_t)(R + c) << 6) + hh * 32 + q * 8, ahi, alo);
            #pragma unroll
            for (int t = 0; t < 4; t++) { MFMA3R(cc[t], ahi, alo, bhi, blo, t, hh); }
        }
        float ss[4];
        #pragma unroll
        for (int r = 0; r < 4; r++) {
            #pragma unroll
            for (int t = 0; t < 4; t++) cc[t][r] += badd[t];
            ss[r] = cc[0][r] * cc[0][r] + cc[1][r] * cc[1][r] +
                    cc[2][r] * cc[2][r] + cc[3][r] * cc[3][r];
        }
        #pragma unroll
        for (int off = 1; off <= 8; off <<= 1) {
            #pragma unroll
            for (int r = 0; r < 4; r++) ss[r] += __shfl_xor(ss[r], off, 64);
        }
        #pragma unroll
        for (int r = 0; r < 4; r++) {
            float sc = 1.0f / (sqrtf(ss[r]) + EPS);
            int row = R + q * 4 + r;
            #pragma unroll
            for (int t = 0; t < 4; t++)
                h0b[(size_t)row * DD + t * 16 + c] = f2bf(cc[t][r] * sc);
        }
    }
}

// blocks [0,512): bucket-histogram + rows 0..3 neighbor lists; last-arriving
// histogram block (atomic ticket) performs the 1024-bucket exclusive scan
// in-kernel (replaces the k_scan1024 launch).
// blocks [512,768): l0 GEMM tiles [0,TILEA).
__global__ __launch_bounds__(256, 3) void k_histoGemmA(const int* __restrict__ ei,
                                                       int* __restrict__ bhist,
                                                       const float* __restrict__ x,
                                                       const float* __restrict__ W0,
                                                       const float* __restrict__ b0,
                                                       unsigned short* __restrict__ h0b,
                                                       int* __restrict__ lbctr,
                                                       int* __restrict__ bstart,
                                                       int* __restrict__ gcur,
                                                       int* __restrict__ scur,
                                                       int* __restrict__ cnt4,
                                                       int* __restrict__ list4) {
    __shared__ int h[NBUCK];
    __shared__ int wtot[4];
    __shared__ int lastf;
    if (blockIdx.x < 512) {
        for (int i = threadIdx.x; i < NBUCK; i += 256) h[i] = 0;
        __syncthreads();
        int tid = blockIdx.x * 256 + threadIdx.x;
        int stride = 512 * 256;
        for (int e = tid; e < NEDGES; e += stride) {
            int d = ei[NEDGES + e];
            atomicAdd(&h[(unsigned)d / BW], 1);
            if ((unsigned)d < 4u) {
                int s = ei[e];
                int p = atomicAdd(&cnt4[d], 1);
                if (p < CAP4) list4[d * CAP4 + p] = s;
            }
        }
        __syncthreads();
        for (int i = threadIdx.x; i < NBUCK; i += 256)
            if (h[i]) atomicAdd(&bhist[i], h[i]);
        // ---- last-arriving histogram block: exclusive scan of bhist ----
        __threadfence();
        if (threadIdx.x == 0) lastf = (atomicAdd(lbctr, 1) == 511);
        __syncthreads();
        if (!lastf) return;
        __threadfence();
        int t = threadIdx.x;                 // 256 threads x 4 buckets each
        int v[4];
        int s = 0;
        #pragma unroll
        for (int k = 0; k < 4; k++) {
            v[k] = atomicAdd(&bhist[t * 4 + k], 0);   // device-coherent read
            s += v[k];
        }
        int lane = t & 63, w = t >> 6;
        int inc = s;
        #pragma unroll
        for (int off = 1; off < 64; off <<= 1) {
            int u = __shfl_up(inc, off, 64);
            if (lane >= off) inc += u;
        }
        if (lane == 63) wtot[w] = inc;
        __syncthreads();
        int wbase = 0;
        for (int i = 0; i < w; i++) wbase += wtot[i];
        int run = wbase + inc - s;
        #pragma unroll
        for (int k = 0; k < 4; k++) {
            bstart[t * 4 + k] = run;
            gcur[t * 4 + k] = run;
            run += v[k];
        }
        if (t == 0) scur[0] = 0;
        return;
    }
    int bid = blockIdx.x - 512;                   // 256 GEMM blocks
    int wid = (bid * 256 + threadIdx.x) >> 6;     // 1024 waves
    l0_tiles(x, W0, b0, h0b, threadIdx.x & 63, wid, 1024, 0, TILEA);
}

// blocks [0,BIN_BLOCKS): bin edges into per-bucket dense runs;
// blocks [BIN_BLOCKS, BIN_BLOCKS+1024): l0 GEMM tiles [TILEA, NTILES).
__global__ __launch_bounds__(256, 3) void k_binGemmB(const float* __restrict__ x,
                                                     const float* __restrict__ W0,
                                                     const float* __restrict__ b0,
                                                     unsigned short* __restrict__ h0b,
                                                     const int* __restrict__ ei,
                                                     int* __restrict__ gcur,
                                                     unsigned* __restrict__ colpack) {
    __shared__ unsigned stag[NBUCK * BIN_CAP];   // 48 KB (bin blocks only)
    __shared__ int lcnt[NBUCK];                  // 4 KB
    int t = threadIdx.x;
    if (blockIdx.x < BIN_BLOCKS) {
        for (int i = t; i < NBUCK; i += 256) lcnt[i] = 0;
        __syncthreads();
        int lo = blockIdx.x * BIN_CHUNK;
        int hi = lo + BIN_CHUNK; if (hi > NEDGES) hi = NEDGES;
        for (int e = lo + t; e < hi; e += 256) {
            int d = ei[NEDGES + e];
            int s = ei[e];
            unsigned b = (unsigned)d / BW;
            unsigned dl = (unsigned)d - b * BW;
            unsigned pk = ((unsigned)s << 8) | dl;
            int slot = atomicAdd(&lcnt[b], 1);
            if (slot < BIN_CAP) {
                stag[b * BIN_CAP + slot] = pk;
            } else {
                colpack[atomicAdd(&gcur[b], 1)] = pk;
            }
        }
        __syncthreads();
        for (int b = t; b < NBUCK; b += 256) {
            int cnt = lcnt[b];
            if (cnt > BIN_CAP) cnt = BIN_CAP;
            if (cnt > 0) {
                int base = atomicAdd(&gcur[b], cnt);
                for (int i = 0; i < cnt; i++)
                    colpack[base + i] = stag[b * BIN_CAP + i];
            }
        }
        return;
    }
    int bid = blockIdx.x - BIN_BLOCKS;            // 1024 GEMM blocks
    int wid = (bid * 256 + t) >> 6;               // 4096 waves
    l0_tiles(x, W0, b0, h0b, t & 63, wid, 4096, TILEA, NTILES);
}

// grid = NBUCK (1024) blocks of 512 threads.
// block 0: head — rows 0..3 full pipeline in fp32 -> scal.
// blocks [1,NBUCK): bucket b = blockIdx.x-1. Two-pass counting-sort into LDS,
// wave-parallel exclusive scan, then gather-aggregate processing FOUR nodes
// per wave iteration (4 independent lcol reads + 4 independent us8 loads).
__global__ __launch_bounds__(512, 4) void k_sortAggH(const unsigned* __restrict__ colpack,
                                                     const int* __restrict__ bstart,
                                                     const int* __restrict__ bhist,
                                                     const unsigned short* __restrict__ h0b,
                                                     float* __restrict__ agg,
                                                     int* __restrict__ scratch,
                                                     int* __restrict__ scratch_cur,
                                                     const float* __restrict__ x,
                                                     const float* __restrict__ W0,
                                                     const float* __restrict__ b0,
                                                     const int* __restrict__ cnt4,
                                                     const int* __restrict__ list4,
                                                     const float* __restrict__ Wm,
                                                     const float* __restrict__ bm,
                                                     const float* __restrict__ W1,
                                                     const float* __restrict__ b1,
                                                     float* __restrict__ scal) {
    __shared__ int lcol[SORT_CAP];   // 16 KB; head aliases its [4][64] arrays here
    __shared__ int cnt[BW];
    __shared__ int pre[BW];
    __shared__ int sbs;
    int t = threadIdx.x;
    if (blockIdx.x == 0) {
        // ---- head (rows 0..3, fp32-exact); waves 4..7 only keep barriers alive ----
        float* hs  = (float*)lcol;          // [4][64]
        float* h2s = hs + 4 * DD;
        float* frs = h2s + 4 * DD;
        int lane = t & 63;
        int w = t >> 6;                      // 0..7; compute only for w<4
        float sgn = (lane == 63) ? -1.0f : 1.0f;
        float s1 = 1.0f;
        float cr_init = 0.0f;
        if (w < 4) {
            float w0[DD];
            #pragma unroll
            for (int k = 0; k < DD; k++) w0[k] = W0[k * DD + lane];
            float b0v = b0[lane];
            auto h0row = [&](int r) -> float {
                float xv = x[(size_t)r * DD + lane];
                float acc = b0v;
                #pragma unroll
                for (int k = 0; k < DD; k++)
                    acc = fmaf(bcast(xv, k), w0[k], acc);
                float n = sqrtf(wave_sum(acc * acc));
                return acc / (n + EPS);
            };
            hs[w * DD + lane] = h0row(w);
            int full = cnt4[w];
            int cl = full; if (cl > CAP4) cl = CAP4;
            float sum = 0.0f;
            for (int i = 0; i < cl; i++) sum += h0row(list4[w * CAP4 + i]);
            float av = sum / fmaxf((float)full, 1.0f);
            float acc = bm[lane];
            #pragma unroll
            for (int k = 0; k < DD; k++)
                acc = fmaf(bcast(av, k), Wm[k * DD + lane], acc);
            float n = sqrtf(wave_sum(acc * acc));
            h2s[w * DD + lane] = acc / (n + EPS);
        }
        __syncthreads();
        if (w < 4) {
            cr_init = cross_ratio(x[lane], x[DD + lane], x[2 * DD + lane], x[3 * DD + lane], sgn);
            float cr0 = cross_ratio(hs[lane], hs[DD + lane], hs[2 * DD + lane], hs[3 * DD + lane], sgn);
            float cr_cur = cross_ratio(h2s[lane], h2s[DD + lane], h2s[2 * DD + lane], h2s[3 * DD + lane], sgn);
            s1 = restore_scale(cr0, cr_cur);
            float hv = h2s[w * DD + lane] * s1;
            float acc2 = b1[lane];
            #pragma unroll
            for (int k = 0; k < DD; k++)
                acc2 = fmaf(bcast(hv, k), W1[k * DD + lane], acc2);
            float n = sqrtf(wave_sum(acc2 * acc2));
            frs[w * DD + lane] = fmaxf(acc2 / (n + EPS), 0.0f);
        }
        __syncthreads();
        if (w == 0) {
            float cr2 = cross_ratio(frs[lane], frs[DD + lane], frs[2 * DD + lane], frs[3 * DD + lane], sgn);
            float s2 = restore_scale(cr_init, cr2);
            if (lane == 0) { scal[0] = s1; scal[1] = s2; }
        }
        return;
    }
    // ---- per-bucket ----
    int b = blockIdx.x - 1;
    int nlo = b * BW; if (nlo > NNODES) nlo = NNODES;
    int nhi = nlo + BW; if (nhi > NNODES) nhi = NNODES;
    int nodes = nhi - nlo;
    int base = bstart[b];
    int n = bhist[b];
    for (int i = t; i < BW; i += 512) cnt[i] = 0;
    bool inLds = (n <= SORT_CAP);
    if (t == 0) sbs = inLds ? 0 : atomicAdd(scratch_cur, n);
    __syncthreads();
    int sb = sbs;
    // pass 1: local-dst histogram
    for (int i = t; i < n; i += 512)
        atomicAdd(&cnt[colpack[base + i] & 255u], 1);
    __syncthreads();
    // wave 0: exclusive scan over BW=98 counters (two 64-wide shfl scans)
    if (t < 64) {
        int v0 = cnt[t];
        int inc0 = v0;
        #pragma unroll
        for (int off = 1; off < 64; off <<= 1) {
            int u = __shfl_up(inc0, off, 64);
            if (t >= off) inc0 += u;
        }
        int tot0 = __builtin_amdgcn_readlane(inc0, 63);
        int ex0 = inc0 - v0;
        int i1 = 64 + t;
        int v1 = (i1 < BW) ? cnt[i1] : 0;
        int inc1 = v1;
        #pragma unroll
        for (int off = 1; off < 64; off <<= 1) {
            int u = __shfl_up(inc1, off, 64);
            if (t >= off) inc1 += u;
        }
        int ex1 = inc1 - v1 + tot0;
        pre[t] = ex0;
        cnt[t] = ex0;
        if (i1 < BW) { pre[i1] = ex1; cnt[i1] = ex1; }
    }
    __syncthreads();
    // pass 2: placement (colpack re-read is L2-hot)
    for (int i = t; i < n; i += 512) {
        unsigned pk = colpack[base + i];
        int pos = atomicAdd(&cnt[pk & 255u], 1);
        int v = (int)(pk >> 8);
        if (inLds) lcol[pos] = v;
        else       scratch[sb + pos] = v;
    }
    __syncthreads();
    // ---- gather-aggregate: 4-node, unified predicated group loop ----
    int wv = t >> 6, lane = t & 63;
    int q = lane & 7, g = lane >> 3;
    auto run_agg = [&](auto ld) {
        for (int dA = wv; dA < nodes; dA += 32) {
            int dB = dA + 8, dC = dA + 16, dD = dA + 24;
            bool hB = dB < nodes, hC = dC < nodes, hD = dD < nodes;
            int stA = pre[dA], enA = cnt[dA];        // cnt = pre + degree
            int stB = hB ? pre[dB] : 0, enB = hB ? cnt[dB] : 0;
            int stC = hC ? pre[dC] : 0, enC = hC ? cnt[dC] : 0;
            int stD = hD ? pre[dD] : 0, enD = hD ? cnt[dD] : 0;
            int ngA = (enA - stA + 7) >> 3, ngB = (enB - stB + 7) >> 3;
            int ngC = (enC - stC + 7) >> 3, ngD = (enD - stD + 7) >> 3;
            int ng = ngA > ngB ? ngA : ngB;
            if (ngC > ng) ng = ngC;
            if (ngD > ng) ng = ngD;
            float sA[8] = {0, 0, 0, 0, 0, 0, 0, 0};
            float sB[8] = {0, 0, 0, 0, 0, 0, 0, 0};
            float sC[8] = {0, 0, 0, 0, 0, 0, 0, 0};
            float sD[8] = {0, 0, 0, 0, 0, 0, 0, 0};
            for (int k = 0; k < ng; k++) {
                int eA = stA + k * 8 + g;
                int eB = stB + k * 8 + g;
                int eC = stC + k * 8 + g;
                int eD = stD + k * 8 + g;
                bool fA = eA < enA, fB = eB < enB, fC = eC < enC, fD = eD < enD;
                int iA = ld(fA ? eA : 0);
                int iB = ld(fB ? eB : 0);
                int iC = ld(fC ? eC : 0);
                int iD = ld(fD ? eD : 0);
                us8 uA = *(const us8*)(h0b + (size_t)iA * DD + q * 8);
                us8 uB = *(const us8*)(h0b + (size_t)iB * DD + q * 8);
                us8 uC = *(const us8*)(h0b + (size_t)iC * DD + q * 8);
                us8 uD = *(const us8*)(h0b + (size_t)iD * DD + q * 8);
                float mA = fA ? 1.0f : 0.0f;
                float mB = fB ? 1.0f : 0.0f;
                float mC = fC ? 1.0f : 0.0f;
                float mD = fD ? 1.0f : 0.0f;
                #pragma unroll
                for (int i = 0; i < 8; i++) {
                    sA[i] = fmaf(mA, bf2f(uA[i]), sA[i]);
                    sB[i] = fmaf(mB, bf2f(uB[i]), sB[i]);
                    sC[i] = fmaf(mC, bf2f(uC[i]), sC[i]);
                    sD[i] = fmaf(mD, bf2f(uD[i]), sD[i]);
                }
            }
            #pragma unroll
            for (int i = 0; i < 8; i++) {
                sA[i] += __shfl_xor(sA[i], 8, 64);
                sA[i] += __shfl_xor(sA[i], 16, 64);
                sA[i] += __shfl_xor(sA[i], 32, 64);
                sB[i] += __shfl_xor(sB[i], 8, 64);
                sB[i] += __shfl_xor(sB[i], 16, 64);
                sB[i] += __shfl_xor(sB[i], 32, 64);
                sC[i] += __shfl_xor(sC[i], 8, 64);
                sC[i] += __shfl_xor(sC[i], 16, 64);
                sC[i] += __shfl_xor(sC[i], 32, 64);
                sD[i] += __shfl_xor(sD[i], 8, 64);
                sD[i] += __shfl_xor(sD[i], 16, 64);
                sD[i] += __shfl_xor(sD[i], 32, 64);
            }
            if (g == 0) {
                float invA = 1.0f / fmaxf((float)(enA - stA), 1.0f);
                float4* dstA = (float4*)(agg + (size_t)(nlo + dA) * DD + q * 8);
                float4 a0 = {sA[0] * invA, sA[1] * invA, sA[2] * invA, sA[3] * invA};
                float4 a1 = {sA[4] * invA, sA[5] * invA, sA[6] * invA, sA[7] * invA};
                dstA[0] = a0;
                dstA[1] = a1;
                if (hB) {
                    float invB = 1.0f / fmaxf((float)(enB - stB), 1.0f);
                    float4* dstB = (float4*)(agg + (size_t)(nlo + dB) * DD + q * 8);
                    float4 b0v = {sB[0] * invB, sB[1] * invB, sB[2] * invB, sB[3] * invB};
                    float4 b1v = {sB[4] * invB, sB[5] * invB, sB[6] * invB, sB[7] * invB};
                    dstB[0] = b0v;
                    dstB[1] = b1v;
                }
                if (hC) {
                    float invC = 1.0f / fmaxf((float)(enC - stC), 1.0f);
                    float4* dstC = (float4*)(agg + (size_t)(nlo + dC) * DD + q * 8);
                    float4 c0 = {sC[0] * invC, sC[1] * invC, sC[2] * invC, sC[3] * invC};
                    float4 c1 = {sC[4] * invC, sC[5] * invC, sC[6] * invC, sC[7] * invC};
                    dstC[0] = c0;
                    dstC[1] = c1;
                }
                if (hD) {
                    float invD = 1.0f / fmaxf((float)(enD - stD), 1.0f);
                    float4* dstD = (float4*)(agg + (size_t)(nlo + dD) * DD + q * 8);
                    float4 d0 = {sD[0] * invD, sD[1] * invD, sD[2] * invD, sD[3] * invD};
                    float4 d1 = {sD[4] * invD, sD[5] * invD, sD[6] * invD, sD[7] * invD};
                    dstD[0] = d0;
                    dstD[1] = d1;
                }
            }
        }
    };
    if (inLds) run_agg([&](int e) { return lcol[e]; });
    else       run_agg([&](int e) { return scratch[sb + e]; });
}

// data = s1 * normalize(data @ Wm + bm), in place. One fragment set -> (256,4).
__global__ __launch_bounds__(256, 4) void k_gemmM(float* data,
                                                  const float* __restrict__ Wm,
                                                  const float* __restrict__ bm,
                                                  const float* __restrict__ scal) {
    int tid = threadIdx.x;
    int lane = tid & 63;
    int c = lane & 15, q = lane >> 4;
    short8 bhi[4][2], blo[4][2];
    load_bfrags(Wm, lane, bhi, blo);
    float badd[4];
    #pragma unroll
    for (int t = 0; t < 4; t++) badd[t] = bm[t * 16 + c];
    float s1 = scal[0];
    int wid = (blockIdx.x * 256 + tid) >> 6;
    int nw = (gridDim.x * 256) >> 6;
    for (int tile = wid; tile < NTILES; tile += nw) {
        int R = tile * 16;
        f32x4 cc[4] = {{0, 0, 0, 0}, {0, 0, 0, 0}, {0, 0, 0, 0}, {0, 0, 0, 0}};
        #pragma unroll
        for (int hh = 0; hh < 2; hh++) {
            short8 ahi, alo;
            build_a(data + ((size_t)(R + c) << 6) + hh * 32 + q * 8, ahi, alo);
            #pragma unroll
            for (int t = 0; t < 4; t++) { MFMA3R(cc[t], ahi, alo, bhi, blo, t, hh); }
        }
        float ss[4];
        #pragma unroll
        for (int r = 0; r < 4; r++) {
            #pragma unroll
            for (int t = 0; t < 4; t++) cc[t][r] += badd[t];
            ss[r] = cc[0][r] * cc[0][r] + cc[1][r] * cc[1][r] +
                    cc[2][r] * cc[2][r] + cc[3][r] * cc[3][r];
        }
        #pragma unroll
        for (int off = 1; off <= 8; off <<= 1) {
            #pragma unroll
            for (int r = 0; r < 4; r++) ss[r] += __shfl_xor(ss[r], off, 64);
        }
        #pragma unroll
        for (int r = 0; r < 4; r++) {
            float sc = s1 / (sqrtf(ss[r]) + EPS);
            int row = R + q * 4 + r;
            #pragma unroll
            for (int t = 0; t < 4; t++)
                data[(size_t)row * DD + t * 16 + c] = cc[t][r] * sc;
        }
    }
}

// data = s2 * relu(normalize(data @ W1 + b1)), in place. One fragment set -> (256,4).
__global__ __launch_bounds__(256, 4) void k_gemm1(float* data,
                                                  const float* __restrict__ W1,
                                                  const float* __restrict__ b1,
                                                  const float* __restrict__ scal) {
    int tid = threadIdx.x;
    int lane = tid & 63;
    int c = lane & 15, q = lane >> 4;
    short8 bhi[4][2], blo[4][2];
    load_bfrags(W1, lane, bhi, blo);
    float badd[4];
    #pragma unroll
    for (int t = 0; t < 4; t++) badd[t] = b1[t * 16 + c];
    float s2 = scal[1];
    int wid = (blockIdx.x * 256 + tid) >> 6;
    int nw = (gridDim.x * 256) >> 6;
    for (int tile = wid; tile < NTILES; tile += nw) {
        int R = tile * 16;
        f32x4 cc[4] = {{0, 0, 0, 0}, {0, 0, 0, 0}, {0, 0, 0, 0}, {0, 0, 0, 0}};
        #pragma unroll
        for (int hh = 0; hh < 2; hh++) {
            short8 ahi, alo;
            build_a(data + ((size_t)(R + c) << 6) + hh * 32 + q * 8, ahi, alo);
            #pragma unroll
            for (int t = 0; t < 4; t++) { MFMA3R(cc[t], ahi, alo, bhi, blo, t, hh); }
        }
        float ss[4];
        #pragma unroll
        for (int r = 0; r < 4; r++) {
            #pragma unroll
            for (int t = 0; t < 4; t++) cc[t][r] += badd[t];
            ss[r] = cc[0][r] * cc[0][r] + cc[1][r] * cc[1][r] +
                    cc[2][r] * cc[2][r] + cc[3][r] * cc[3][r];
        }
        #pragma unroll
        for (int off = 1; off <= 8; off <<= 1) {
            #pragma unroll
            for (int r = 0; r < 4; r++) ss[r] += __shfl_xor(ss[r], off, 64);
        }
        #pragma unroll
        for (int r = 0; r < 4; r++) {
            float sc = 1.0f / (sqrtf(ss[r]) + EPS);
            int row = R + q * 4 + r;
            #pragma unroll
            for (int t = 0; t < 4; t++)
                data[(size_t)row * DD + t * 16 + c] = fmaxf(cc[t][r] * sc, 0.0f) * s2;
        }
    }
}

extern "C" void kernel_launch(void* const* d_in, const int* in_sizes, int n_in,
                              void* d_out, int out_size, void* d_ws, size_t ws_size,
                              hipStream_t stream) {
    const float* x  = (const float*)d_in[0];
    const int*   ei = (const int*)d_in[1];
    const float* W0 = (const float*)d_in[2];
    const float* b0 = (const float*)d_in[3];
    const float* Wm = (const float*)d_in[4];
    const float* bm = (const float*)d_in[5];
    const float* W1 = (const float*)d_in[6];
    const float* b1 = (const float*)d_in[7];
    float* out = (float*)d_out;

    // ws layout (~19.7 MB)
    unsigned short* h0b = (unsigned short*)d_ws;                 // N*64 bf16 = 12.8 MB
    int* scratch = (int*)(h0b + (size_t)NNODES * DD);            // N (sort overflow scratch)
    unsigned* colpack = (unsigned*)(scratch + NNODES);           // E = 6.4 MB
    int* bhist  = (int*)(colpack + NEDGES);                      // 1024
    int* cnt4   = bhist + NBUCK;                                 // 4
    int* lbctr  = cnt4 + 4;                                      // 1 (last-block ticket)
    int* bstart = lbctr + 1;                                     // 1024
    int* gcur   = bstart + NBUCK;                                // 1024
    int* scur   = gcur + NBUCK;                                  // 1
    int* list4  = scur + 1;                                      // 4*512
    float* scal = (float*)(list4 + 4 * CAP4);                    // 2

    (void)hipMemsetAsync(bhist, 0, (NBUCK + 5) * sizeof(int), stream);  // bhist+cnt4+lbctr

    k_histoGemmA<<<512 + 256, 256, 0, stream>>>(ei, bhist, x, W0, b0, h0b,
                                                lbctr, bstart, gcur, scur, cnt4, list4);
    k_binGemmB  <<<BIN_BLOCKS + 1024, 256, 0, stream>>>(x, W0, b0, h0b, ei, gcur, colpack);
    k_sortAggH  <<<NBUCK, 512, 0, stream>>>(colpack, bstart, bhist, h0b, out, scratch, scur,
                                            x, W0, b0, cnt4, list4, Wm, bm, W1, b1, scal);
    k_gemmM     <<<1024, 256, 0, stream>>>(out, Wm, bm, scal);
    k_gemm1     <<<1024, 256, 0, stream>>>(out, W1, b1, scal);
}

// Round 10
// 181.877 us; speedup vs baseline: 1.4066x; 1.4066x over previous
//
#include <hip/hip_runtime.h>
#include <math.h>

#define NNODES 100000
#define NEDGES 1600000
#define DD 64
#define EPS 1e-8f

#define NBUCK 1024
#define BW 98
#define BIN_BLOCKS 256
#define BIN_CHUNK ((NEDGES + BIN_BLOCKS - 1) / BIN_BLOCKS)  // 6250
#define BIN_CAP 12
#define CAPB 1792              // fixed colpack slots per bucket (mean 1568, +5.7 sigma)
#define SORT_CAP 4096
#define NTILES (NNODES / 16)   // 6250, exact
#define CAP4 512
#define TSTR 68                // LDS transpose row stride (floats)

typedef unsigned short us8 __attribute__((ext_vector_type(8)));
typedef short short8 __attribute__((ext_vector_type(8)));
typedef float f32x4 __attribute__((ext_vector_type(4)));

__device__ __forceinline__ float wave_sum(float v) {
    #pragma unroll
    for (int off = 32; off; off >>= 1) v += __shfl_xor(v, off, 64);
    return v;
}

__device__ __forceinline__ float hinner(float u, float v, float sgn) {
    return wave_sum(sgn * u * v);
}

__device__ __forceinline__ float cross_ratio(float r0, float r1, float r2, float r3, float sgn) {
    float A = hinner(r0, r2, sgn);
    float B = hinner(r1, r3, sgn);
    float C = hinner(r0, r3, sgn);
    float Dv = hinner(r1, r2, sgn);
    return (A * B) / (C * Dv + EPS);
}

__device__ __forceinline__ float restore_scale(float cr_i, float cr_c) {
    float ratio = cr_i / (cr_c + EPS);
    bool cond = (!__builtin_isnan(cr_c)) && (!__builtin_isnan(cr_i)) &&
                (fabsf(cr_c) > EPS) && (fabsf(cr_i) > EPS) && (ratio > EPS);
    float s = 1.0f;
    if (cond) {
        s = sqrtf(fabsf(ratio));
        if (!__builtin_isfinite(s)) s = 1.0f;
    }
    return s;
}

__device__ __forceinline__ unsigned short f2bf(float f) {
    unsigned u = __float_as_uint(f);
    unsigned r = (u + 0x7fffu + ((u >> 16) & 1u)) >> 16;
    return (unsigned short)r;
}

__device__ __forceinline__ float bf2f(unsigned short b) {
    return __uint_as_float(((unsigned)b) << 16);
}

__device__ __forceinline__ float bcast(float v, int lane) {
    return __int_as_float(__builtin_amdgcn_readlane(__float_as_int(v), lane));
}

// load one weight matrix as split-bf16 B fragments in VGPRs
__device__ __forceinline__ void load_bfrags(const float* __restrict__ W, int lane,
                                            short8 bhi[4][2], short8 blo[4][2]) {
    int c = lane & 15, q = lane >> 4;
    #pragma unroll
    for (int t = 0; t < 4; t++)
        #pragma unroll
        for (int h = 0; h < 2; h++) {
            short8 hi8, lo8;
            #pragma unroll
            for (int j = 0; j < 8; j++) {
                float w = W[(h * 32 + q * 8 + j) * DD + t * 16 + c];
                unsigned short hb = f2bf(w);
                float r = w - bf2f(hb);
                hi8[j] = (short)hb;
                lo8[j] = (short)f2bf(r);
            }
            bhi[t][h] = hi8;
            blo[t][h] = lo8;
        }
}

__device__ __forceinline__ void build_a8(const float av[8], short8& hi, short8& lo) {
    short8 h8, l8;
    #pragma unroll
    for (int j = 0; j < 8; j++) {
        unsigned short hb = f2bf(av[j]);
        float r = av[j] - bf2f(hb);
        h8[j] = (short)hb;
        l8[j] = (short)f2bf(r);
    }
    hi = h8;
    lo = l8;
}

__device__ __forceinline__ void build_a(const float* p, short8& hi, short8& lo) {
    float4 f0 = *(const float4*)p;
    float4 f1 = *(const float4*)(p + 4);
    float av[8] = {f0.x, f0.y, f0.z, f0.w, f1.x, f1.y, f1.z, f1.w};
    build_a8(av, hi, lo);
}

#define MFMA3R(cacc, ahi, alo, BH, BL, t, h)                                     \
    cacc = __builtin_amdgcn_mfma_f32_16x16x32_bf16(ahi, BH[t][h], cacc, 0, 0, 0); \
    cacc = __builtin_amdgcn_mfma_f32_16x16x32_bf16(alo, BH[t][h], cacc, 0, 0, 0); \
    cacc = __builtin_amdgcn_mfma_f32_16x16x32_bf16(ahi, BL[t][h], cacc, 0, 0, 0);

// shared GEMM-tile body for the l0 layer (x@W0 -> normalize -> h0b bf16)
__device__ __forceinline__ void l0_tiles(const float* __restrict__ x,
                                         const float* __restrict__ W0,
                                         const float* __restrict__ b0,
                                         unsigned short* __restrict__ h0b,
                                         int lane, int wid, int nw, int tlo, int thi) {
    int c = lane & 15, q = lane >> 4;
    short8 bhi[4][2], blo[4][2];
    load_bfrags(W0, lane, bhi, blo);
    float badd[4];
    #pragma unroll
    for (int t = 0; t < 4; t++) badd[t] = b0[t * 16 + c];
    for (int tile = tlo + wid; tile < thi; tile += nw) {
        int R = tile * 16;
        f32x4 cc[4] = {{0, 0, 0, 0}, {0, 0, 0, 0}, {0, 0, 0, 0}, {0, 0, 0, 0}};
        #pragma unroll
        for (int hh = 0; hh < 2; hh++) {
            short8 ahi, alo;
            build_a(x + ((size_t)(R + c) << 6) + hh * 32 + q * 8, ahi, alo);
            #pragma unroll
            for (int t = 0; t < 4; t++) { MFMA3R(cc[t], ahi, alo, bhi, blo, t, hh); }
        }
        float ss[4];
        #pragma unroll
        for (int r = 0; r < 4; r++) {
            #pragma unroll
            for (int t = 0; t < 4; t++) cc[t][r] += badd[t];
            ss[r] = cc[0][r] * cc[0][r] + cc[1][r] * cc[1][r] +
                    cc[2][r] * cc[2][r] + cc[3][r] * cc[3][r];
        }
        #pragma unroll
        for (int off = 1; off <= 8; off <<= 1) {
            #pragma unroll
            for (int r = 0; r < 4; r++) ss[r] += __shfl_xor(ss[r], off, 64);
        }
        #pragma unroll
        for (int r = 0; r < 4; r++) {
            float sc = 1.0f / (sqrtf(ss[r]) + EPS);
            int row = R + q * 4 + r;
            #pragma unroll
            for (int t = 0; t < 4; t++)
                h0b[(size_t)row * DD + t * 16 + c] = f2bf(cc[t][r] * sc);
        }
    }
}

// blocks [0,BIN_BLOCKS): bin edges into fixed-stride per-bucket regions
// (colpack[b*CAPB + cursor[b]++]) — no histogram, no scan needed, cursor
// zero-init by memset. Also collects rows 0..3 neighbor lists.
// blocks [BIN_BLOCKS, BIN_BLOCKS+1024): ALL l0 GEMM tiles [0, NTILES).
__global__ __launch_bounds__(256, 3) void k_binGemm(const float* __restrict__ x,
                                                    const float* __restrict__ W0,
                                                    const float* __restrict__ b0,
                                                    unsigned short* __restrict__ h0b,
                                                    const int* __restrict__ ei,
                                                    int* __restrict__ cursor,
                                                    unsigned* __restrict__ colpack,
                                                    int* __restrict__ cnt4,
                                                    int* __restrict__ list4) {
    __shared__ unsigned stag[NBUCK * BIN_CAP];   // 48 KB (bin blocks only)
    __shared__ int lcnt[NBUCK];                  // 4 KB
    int t = threadIdx.x;
    if (blockIdx.x < BIN_BLOCKS) {
        for (int i = t; i < NBUCK; i += 256) lcnt[i] = 0;
        __syncthreads();
        int lo = blockIdx.x * BIN_CHUNK;
        int hi = lo + BIN_CHUNK; if (hi > NEDGES) hi = NEDGES;
        for (int e = lo + t; e < hi; e += 256) {
            int d = ei[NEDGES + e];
            int s = ei[e];
            if ((unsigned)d < 4u) {
                int p = atomicAdd(&cnt4[d], 1);
                if (p < CAP4) list4[d * CAP4 + p] = s;
            }
            unsigned b = (unsigned)d / BW;
            unsigned dl = (unsigned)d - b * BW;
            unsigned pk = ((unsigned)s << 8) | dl;
            int slot = atomicAdd(&lcnt[b], 1);
            if (slot < BIN_CAP) {
                stag[b * BIN_CAP + slot] = pk;
            } else {
                colpack[b * CAPB + atomicAdd(&cursor[b], 1)] = pk;
            }
        }
        __syncthreads();
        for (int b = t; b < NBUCK; b += 256) {
            int cnt = lcnt[b];
            if (cnt > BIN_CAP) cnt = BIN_CAP;
            if (cnt > 0) {
                int base = b * CAPB + atomicAdd(&cursor[b], cnt);
                for (int i = 0; i < cnt; i++)
                    colpack[base + i] = stag[b * BIN_CAP + i];
            }
        }
        return;
    }
    int bid = blockIdx.x - BIN_BLOCKS;            // 1024 GEMM blocks
    int wid = (bid * 256 + t) >> 6;               // 4096 waves
    l0_tiles(x, W0, b0, h0b, t & 63, wid, 4096, 0, NTILES);
}

// grid = NBUCK (1024) blocks of 512 threads.
// block 0: head — rows 0..3 full pipeline in fp32 -> scal.
// blocks [1,NBUCK): bucket b = blockIdx.x-1, run at colpack[b*CAPB .. +cursor[b]).
// Two-pass counting-sort into LDS (n <= CAPB < SORT_CAP always), wave-parallel
// exclusive scan, then 4-node gather (4 independent lcol reads + us8 loads).
__global__ __launch_bounds__(512, 4) void k_sortAggH(const unsigned* __restrict__ colpack,
                                                     const int* __restrict__ cursor,
                                                     const unsigned short* __restrict__ h0b,
                                                     float* __restrict__ agg,
                                                     const float* __restrict__ x,
                                                     const float* __restrict__ W0,
                                                     const float* __restrict__ b0,
                                                     const int* __restrict__ cnt4,
                                                     const int* __restrict__ list4,
                                                     const float* __restrict__ Wm,
                                                     const float* __restrict__ bm,
                                                     const float* __restrict__ W1,
                                                     const float* __restrict__ b1,
                                                     float* __restrict__ scal) {
    __shared__ int lcol[SORT_CAP];   // 16 KB; head aliases its [4][64] arrays here
    __shared__ int cnt[BW];
    __shared__ int pre[BW];
    int t = threadIdx.x;
    if (blockIdx.x == 0) {
        // ---- head (rows 0..3, fp32-exact); waves 4..7 only keep barriers alive ----
        float* hs  = (float*)lcol;          // [4][64]
        float* h2s = hs + 4 * DD;
        float* frs = h2s + 4 * DD;
        int lane = t & 63;
        int w = t >> 6;                      // 0..7; compute only for w<4
        float sgn = (lane == 63) ? -1.0f : 1.0f;
        float s1 = 1.0f;
        float cr_init = 0.0f;
        if (w < 4) {
            float w0[DD];
            #pragma unroll
            for (int k = 0; k < DD; k++) w0[k] = W0[k * DD + lane];
            float b0v = b0[lane];
            auto h0row = [&](int r) -> float {
                float xv = x[(size_t)r * DD + lane];
                float acc = b0v;
                #pragma unroll
                for (int k = 0; k < DD; k++)
                    acc = fmaf(bcast(xv, k), w0[k], acc);
                float n = sqrtf(wave_sum(acc * acc));
                return acc / (n + EPS);
            };
            hs[w * DD + lane] = h0row(w);
            int full = cnt4[w];
            int cl = full; if (cl > CAP4) cl = CAP4;
            float sum = 0.0f;
            for (int i = 0; i < cl; i++) sum += h0row(list4[w * CAP4 + i]);
            float av = sum / fmaxf((float)full, 1.0f);
            float acc = bm[lane];
            #pragma unroll
            for (int k = 0; k < DD; k++)
                acc = fmaf(bcast(av, k), Wm[k * DD + lane], acc);
            float n = sqrtf(wave_sum(acc * acc));
            h2s[w * DD + lane] = acc / (n + EPS);
        }
        __syncthreads();
        if (w < 4) {
            cr_init = cross_ratio(x[lane], x[DD + lane], x[2 * DD + lane], x[3 * DD + lane], sgn);
            float cr0 = cross_ratio(hs[lane], hs[DD + lane], hs[2 * DD + lane], hs[3 * DD + lane], sgn);
            float cr_cur = cross_ratio(h2s[lane], h2s[DD + lane], h2s[2 * DD + lane], h2s[3 * DD + lane], sgn);
            s1 = restore_scale(cr0, cr_cur);
            float hv = h2s[w * DD + lane] * s1;
            float acc2 = b1[lane];
            #pragma unroll
            for (int k = 0; k < DD; k++)
                acc2 = fmaf(bcast(hv, k), W1[k * DD + lane], acc2);
            float n = sqrtf(wave_sum(acc2 * acc2));
            frs[w * DD + lane] = fmaxf(acc2 / (n + EPS), 0.0f);
        }
        __syncthreads();
        if (w == 0) {
            float cr2 = cross_ratio(frs[lane], frs[DD + lane], frs[2 * DD + lane], frs[3 * DD + lane], sgn);
            float s2 = restore_scale(cr_init, cr2);
            if (lane == 0) { scal[0] = s1; scal[1] = s2; }
        }
        return;
    }
    // ---- per-bucket ----
    int b = blockIdx.x - 1;
    int nlo = b * BW; if (nlo > NNODES) nlo = NNODES;
    int nhi = nlo + BW; if (nhi > NNODES) nhi = NNODES;
    int nodes = nhi - nlo;
    int base = b * CAPB;
    int n = cursor[b];
    if (n > CAPB) n = CAPB;                      // paranoia clamp (never hit)
    for (int i = t; i < BW; i += 512) cnt[i] = 0;
    __syncthreads();
    // pass 1: local-dst histogram
    for (int i = t; i < n; i += 512)
        atomicAdd(&cnt[colpack[base + i] & 255u], 1);
    __syncthreads();
    // wave 0: exclusive scan over BW=98 counters (two 64-wide shfl scans)
    if (t < 64) {
        int v0 = cnt[t];
        int inc0 = v0;
        #pragma unroll
        for (int off = 1; off < 64; off <<= 1) {
            int u = __shfl_up(inc0, off, 64);
            if (t >= off) inc0 += u;
        }
        int tot0 = __builtin_amdgcn_readlane(inc0, 63);
        int ex0 = inc0 - v0;
        int i1 = 64 + t;
        int v1 = (i1 < BW) ? cnt[i1] : 0;
        int inc1 = v1;
        #pragma unroll
        for (int off = 1; off < 64; off <<= 1) {
            int u = __shfl_up(inc1, off, 64);
            if (t >= off) inc1 += u;
        }
        int ex1 = inc1 - v1 + tot0;
        pre[t] = ex0;
        cnt[t] = ex0;
        if (i1 < BW) { pre[i1] = ex1; cnt[i1] = ex1; }
    }
    __syncthreads();
    // pass 2: placement (colpack re-read is L2-hot)
    for (int i = t; i < n; i += 512) {
        unsigned pk = colpack[base + i];
        int pos = atomicAdd(&cnt[pk & 255u], 1);
        lcol[pos] = (int)(pk >> 8);
    }
    __syncthreads();
    // ---- gather-aggregate: 4-node, unified predicated group loop ----
    int wv = t >> 6, lane = t & 63;
    int q = lane & 7, g = lane >> 3;
    for (int dA = wv; dA < nodes; dA += 32) {
        int dB = dA + 8, dC = dA + 16, dD = dA + 24;
        bool hB = dB < nodes, hC = dC < nodes, hD = dD < nodes;
        int stA = pre[dA], enA = cnt[dA];        // cnt = pre + degree
        int stB = hB ? pre[dB] : 0, enB = hB ? cnt[dB] : 0;
        int stC = hC ? pre[dC] : 0, enC = hC ? cnt[dC] : 0;
        int stD = hD ? pre[dD] : 0, enD = hD ? cnt[dD] : 0;
        int ngA = (enA - stA + 7) >> 3, ngB = (enB - stB + 7) >> 3;
        int ngC = (enC - stC + 7) >> 3, ngD = (enD - stD + 7) >> 3;
        int ng = ngA > ngB ? ngA : ngB;
        if (ngC > ng) ng = ngC;
        if (ngD > ng) ng = ngD;
        float sA[8] = {0, 0, 0, 0, 0, 0, 0, 0};
        float sB[8] = {0, 0, 0, 0, 0, 0, 0, 0};
        float sC[8] = {0, 0, 0, 0, 0, 0, 0, 0};
        float sD[8] = {0, 0, 0, 0, 0, 0, 0, 0};
        for (int k = 0; k < ng; k++) {
            int eA = stA + k * 8 + g;
            int eB = stB + k * 8 + g;
            int eC = stC + k * 8 + g;
            int eD = stD + k * 8 + g;
            bool fA = eA < enA, fB = eB < enB, fC = eC < enC, fD = eD < enD;
            int iA = lcol[fA ? eA : 0];
            int iB = lcol[fB ? eB : 0];
            int iC = lcol[fC ? eC : 0];
            int iD = lcol[fD ? eD : 0];
            us8 uA = *(const us8*)(h0b + (size_t)iA * DD + q * 8);
            us8 uB = *(const us8*)(h0b + (size_t)iB * DD + q * 8);
            us8 uC = *(const us8*)(h0b + (size_t)iC * DD + q * 8);
            us8 uD = *(const us8*)(h0b + (size_t)iD * DD + q * 8);
            float mA = fA ? 1.0f : 0.0f;
            float mB = fB ? 1.0f : 0.0f;
            float mC = fC ? 1.0f : 0.0f;
            float mD = fD ? 1.0f : 0.0f;
            #pragma unroll
            for (int i = 0; i < 8; i++) {
                sA[i] = fmaf(mA, bf2f(uA[i]), sA[i]);
                sB[i] = fmaf(mB, bf2f(uB[i]), sB[i]);
                sC[i] = fmaf(mC, bf2f(uC[i]), sC[i]);
                sD[i] = fmaf(mD, bf2f(uD[i]), sD[i]);
            }
        }
        #pragma unroll
        for (int i = 0; i < 8; i++) {
            sA[i] += __shfl_xor(sA[i], 8, 64);
            sA[i] += __shfl_xor(sA[i], 16, 64);
            sA[i] += __shfl_xor(sA[i], 32, 64);
            sB[i] += __shfl_xor(sB[i], 8, 64);
            sB[i] += __shfl_xor(sB[i], 16, 64);
            sB[i] += __shfl_xor(sB[i], 32, 64);
            sC[i] += __shfl_xor(sC[i], 8, 64);
            sC[i] += __shfl_xor(sC[i], 16, 64);
            sC[i] += __shfl_xor(sC[i], 32, 64);
            sD[i] += __shfl_xor(sD[i], 8, 64);
            sD[i] += __shfl_xor(sD[i], 16, 64);
            sD[i] += __shfl_xor(sD[i], 32, 64);
        }
        if (g == 0) {
            float invA = 1.0f / fmaxf((float)(enA - stA), 1.0f);
            float4* dstA = (float4*)(agg + (size_t)(nlo + dA) * DD + q * 8);
            float4 a0 = {sA[0] * invA, sA[1] * invA, sA[2] * invA, sA[3] * invA};
            float4 a1 = {sA[4] * invA, sA[5] * invA, sA[6] * invA, sA[7] * invA};
            dstA[0] = a0;
            dstA[1] = a1;
            if (hB) {
                float invB = 1.0f / fmaxf((float)(enB - stB), 1.0f);
                float4* dstB = (float4*)(agg + (size_t)(nlo + dB) * DD + q * 8);
                float4 b0v = {sB[0] * invB, sB[1] * invB, sB[2] * invB, sB[3] * invB};
                float4 b1v = {sB[4] * invB, sB[5] * invB, sB[6] * invB, sB[7] * invB};
                dstB[0] = b0v;
                dstB[1] = b1v;
            }
            if (hC) {
                float invC = 1.0f / fmaxf((float)(enC - stC), 1.0f);
                float4* dstC = (float4*)(agg + (size_t)(nlo + dC) * DD + q * 8);
                float4 c0 = {sC[0] * invC, sC[1] * invC, sC[2] * invC, sC[3] * invC};
                float4 c1 = {sC[4] * invC, sC[5] * invC, sC[6] * invC, sC[7] * invC};
                dstC[0] = c0;
                dstC[1] = c1;
            }
            if (hD) {
                float invD = 1.0f / fmaxf((float)(enD - stD), 1.0f);
                float4* dstD = (float4*)(agg + (size_t)(nlo + dD) * DD + q * 8);
                float4 d0 = {sD[0] * invD, sD[1] * invD, sD[2] * invD, sD[3] * invD};
                float4 d1 = {sD[4] * invD, sD[5] * invD, sD[6] * invD, sD[7] * invD};
                dstD[0] = d0;
                dstD[1] = d1;
            }
        }
    }
}

// both GEMMs fused, in place on `data` (=agg):
// H = s1*normalize(data@Wm+bm); out = s2*relu(normalize(H@W1+b1)).
__global__ __launch_bounds__(256, 2) void k_gemm2(float* data,
                                                  const float* __restrict__ Wm,
                                                  const float* __restrict__ bm,
                                                  const float* __restrict__ W1,
                                                  const float* __restrict__ b1,
                                                  const float* __restrict__ scal) {
    __shared__ float tsm[4][16 * TSTR];
    int tid = threadIdx.x;
    int wv = tid >> 6, lane = tid & 63;
    int c = lane & 15, q = lane >> 4;
    short8 bhiM[4][2], bloM[4][2], bhi1[4][2], blo1[4][2];
    load_bfrags(Wm, lane, bhiM, bloM);
    load_bfrags(W1, lane, bhi1, blo1);
    float bmv[4], b1v[4];
    #pragma unroll
    for (int t = 0; t < 4; t++) { bmv[t] = bm[t * 16 + c]; b1v[t] = b1[t * 16 + c]; }
    float s1 = scal[0], s2 = scal[1];
    int wid = (blockIdx.x * 256 + tid) >> 6;
    int nw = (gridDim.x * 256) >> 6;
    for (int tile = wid; tile < NTILES; tile += nw) {
        int R = tile * 16;
        f32x4 cc[4] = {{0, 0, 0, 0}, {0, 0, 0, 0}, {0, 0, 0, 0}, {0, 0, 0, 0}};
        #pragma unroll
        for (int hh = 0; hh < 2; hh++) {
            short8 ahi, alo;
            build_a(data + ((size_t)(R + c) << 6) + hh * 32 + q * 8, ahi, alo);
            #pragma unroll
            for (int t = 0; t < 4; t++) { MFMA3R(cc[t], ahi, alo, bhiM, bloM, t, hh); }
        }
        float ss[4];
        #pragma unroll
        for (int r = 0; r < 4; r++) {
            #pragma unroll
            for (int t = 0; t < 4; t++) cc[t][r] += bmv[t];
            ss[r] = cc[0][r] * cc[0][r] + cc[1][r] * cc[1][r] +
                    cc[2][r] * cc[2][r] + cc[3][r] * cc[3][r];
        }
        #pragma unroll
        for (int off = 1; off <= 8; off <<= 1) {
            #pragma unroll
            for (int r = 0; r < 4; r++) ss[r] += __shfl_xor(ss[r], off, 64);
        }
        #pragma unroll
        for (int r = 0; r < 4; r++) {
            float sc = s1 / (sqrtf(ss[r]) + EPS);
            #pragma unroll
            for (int t = 0; t < 4; t++)
                tsm[wv][(q * 4 + r) * TSTR + t * 16 + c] = cc[t][r] * sc;
        }
        f32x4 c2[4] = {{0, 0, 0, 0}, {0, 0, 0, 0}, {0, 0, 0, 0}, {0, 0, 0, 0}};
        #pragma unroll
        for (int hh = 0; hh < 2; hh++) {
            const float* p = &tsm[wv][c * TSTR + hh * 32 + q * 8];
            float av[8];
            #pragma unroll
            for (int j = 0; j < 8; j++) av[j] = p[j];
            short8 ahi, alo;
            build_a8(av, ahi, alo);
            #pragma unroll
            for (int t = 0; t < 4; t++) { MFMA3R(c2[t], ahi, alo, bhi1, blo1, t, hh); }
        }
        #pragma unroll
        for (int r = 0; r < 4; r++) {
            #pragma unroll
            for (int t = 0; t < 4; t++) c2[t][r] += b1v[t];
            ss[r] = c2[0][r] * c2[0][r] + c2[1][r] * c2[1][r] +
                    c2[2][r] * c2[2][r] + c2[3][r] * c2[3][r];
        }
        #pragma unroll
        for (int off = 1; off <= 8; off <<= 1) {
            #pragma unroll
            for (int r = 0; r < 4; r++) ss[r] += __shfl_xor(ss[r], off, 64);
        }
        #pragma unroll
        for (int r = 0; r < 4; r++) {
            float sc = 1.0f / (sqrtf(ss[r]) + EPS);
            int row = R + q * 4 + r;
            #pragma unroll
            for (int t = 0; t < 4; t++)
                data[(size_t)row * DD + t * 16 + c] = fmaxf(c2[t][r] * sc, 0.0f) * s2;
        }
    }
}

extern "C" void kernel_launch(void* const* d_in, const int* in_sizes, int n_in,
                              void* d_out, int out_size, void* d_ws, size_t ws_size,
                              hipStream_t stream) {
    const float* x  = (const float*)d_in[0];
    const int*   ei = (const int*)d_in[1];
    const float* W0 = (const float*)d_in[2];
    const float* b0 = (const float*)d_in[3];
    const float* Wm = (const float*)d_in[4];
    const float* bm = (const float*)d_in[5];
    const float* W1 = (const float*)d_in[6];
    const float* b1 = (const float*)d_in[7];
    float* out = (float*)d_out;

    // ws layout (~20.2 MB)
    unsigned short* h0b = (unsigned short*)d_ws;                 // N*64 bf16 = 12.8 MB
    unsigned* colpack = (unsigned*)(h0b + (size_t)NNODES * DD);  // NBUCK*CAPB = 7.34 MB
    int* cursor = (int*)(colpack + (size_t)NBUCK * CAPB);        // 1024
    int* cnt4   = cursor + NBUCK;                                // 4
    int* list4  = cnt4 + 4;                                      // 4*512
    float* scal = (float*)(list4 + 4 * CAP4);                    // 2

    (void)hipMemsetAsync(cursor, 0, (NBUCK + 4) * sizeof(int), stream);  // cursor + cnt4

    k_binGemm <<<BIN_BLOCKS + 1024, 256, 0, stream>>>(x, W0, b0, h0b, ei, cursor,
                                                      colpack, cnt4, list4);
    k_sortAggH<<<NBUCK, 512, 0, stream>>>(colpack, cursor, h0b, out,
                                          x, W0, b0, cnt4, list4, Wm, bm, W1, b1, scal);
    k_gemm2   <<<512, 256, 0, stream>>>(out, Wm, bm, W1, b1, scal);
}